// Round 1
// 5548.298 us; speedup vs baseline: 2.3758x; 2.3758x over previous
//
#include <hip/hip_runtime.h>
#include <hip/hip_bf16.h>
#include <math.h>

#define SEQ 512
#define BATCH 64
#define HID 1024
#define G3 3072
#define LAYERS 3
#define JW 16      // hidden dims owned per WG
#define NWGL 64    // WGs per layer group
#define HBLK 65536 // elements per h snapshot: 64 kblocks x 64 batch x 16

typedef __bf16 bf16;
typedef __bf16 bf16x8 __attribute__((ext_vector_type(8)));
typedef __bf16 bf16x4 __attribute__((ext_vector_type(4)));
typedef float f32x4 __attribute__((ext_vector_type(4)));

static __device__ inline bf16x8 cvt_bf8(f32x4 a, f32x4 b) {
  bf16x8 r;
  r[0] = (bf16)a[0]; r[1] = (bf16)a[1]; r[2] = (bf16)a[2]; r[3] = (bf16)a[3];
  r[4] = (bf16)b[0]; r[5] = (bf16)b[1]; r[6] = (bf16)b[2]; r[7] = (bf16)b[3];
  return r;
}

// x[s][b][k] (f32) -> xb[s][k>>4][b][k&15] (bf16): blocked layout matching hbuf.
// Writes fully coalesced (32B/thread contiguous in b); reads 64B-granule gather.
__global__ __launch_bounds__(256) void x_to_bf16_blk(const float* __restrict__ x,
                                                     bf16* __restrict__ xb) {
  const int g = blockIdx.x * 256 + threadIdx.x;
  const int b = g & 63;
  const int kb = (g >> 6) & 63;
  const int s = g >> 12;
  const float* src = x + ((size_t)s * 64 + b) * 1024 + kb * 16;
  bf16* dst = xb + (size_t)s * HBLK + kb * 1024 + b * 16;
  f32x4 a0 = *(const f32x4*)(src);
  f32x4 a1 = *(const f32x4*)(src + 4);
  f32x4 a2 = *(const f32x4*)(src + 8);
  f32x4 a3 = *(const f32x4*)(src + 12);
  *(bf16x8*)(dst) = cvt_bf8(a0, a1);
  *(bf16x8*)(dst + 8) = cvt_bf8(a2, a3);
}

// L1/L2-bypassing 16B load: SGPR base + per-lane 32b voffset + imm offset.
#define GLOAD4(dst, voff, sbase, IMM)                                         \
  asm volatile("global_load_dwordx4 %0, %1, %2 offset:" #IMM " sc0 sc1"       \
               : "=v"(dst) : "v"(voff), "s"(sbase) : "memory")

#define SWAITV(N)                                                             \
  do {                                                                        \
    asm volatile("s_waitcnt vmcnt(" #N ")" ::: "memory");                     \
    __builtin_amdgcn_sched_barrier(0);                                        \
  } while (0)

// R5: fence-free persistent pipelined GRU.
//  - cross-WG h traffic via sc0/sc1 per-access coherence (no buffer_inv/wbl2)
//  - per-WG flag lines, 64-lane single-instruction poll (no atomic RMW)
//  - blocked hbuf layout [kblock][b][16]: coalesced stores, 1KB-span loads
//  - batched load issue + counted vmcnt waits: one L3 latency exposure/phase
__global__ __launch_bounds__(256, 1) void gru_persist(
    const bf16*  __restrict__ xb,    // [SEQ][64 kb][64 b][16] bf16
    const float* __restrict__ h0,    // [LAYERS][BATCH][HID]
    const float* __restrict__ wih,   // [LAYERS*G3][HID]
    const float* __restrict__ whh,   // [LAYERS*G3][HID]
    const float* __restrict__ bih,   // [LAYERS*G3]
    const float* __restrict__ bhh,   // [LAYERS*G3]
    float* __restrict__ out,         // [SEQ][BATCH][HID]
    bf16*  __restrict__ hbuf,        // [LAYERS][2][64 kb][64 b][16] bf16
    int*   __restrict__ flg)         // [LAYERS][NWGL] flags, 32-int stride
{
  const int l    = blockIdx.x >> 6;
  const int wg   = blockIdx.x & 63;
  const int j0   = wg * JW;
  const int tid  = threadIdx.x;
  const int lane = tid & 63, wave = tid >> 6;
  const int quad = lane >> 4, l16 = lane & 15;
  const int kr   = wave * 256;   // this wave's K range

  __shared__ float part[4][3][4][16][18];  // pad 18: uniform 2-way banks (free)
  __shared__ float h_loc[BATCH][20];       // fp32 hidden-state carry, pad 20
  __shared__ float bI[3][JW], bH[3][JW];

  // ---- prologue: both weight slices -> register A-fragments ----
  const float* WhhL = whh + (size_t)l * G3 * HID;
  const float* WihL = wih + (size_t)l * G3 * HID;
  bf16x8 aH[3][8], aI[3][8];
#pragma unroll
  for (int g = 0; g < 3; g++) {
    const int row = g * HID + j0 + l16;
    const float* ph = WhhL + (size_t)row * HID + kr + quad * 8;
    const float* pi = WihL + (size_t)row * HID + kr + quad * 8;
#pragma unroll
    for (int t = 0; t < 8; t++) {
      f32x4 h0v = *(const f32x4*)(ph + t * 32);
      f32x4 h1v = *(const f32x4*)(ph + t * 32 + 4);
      aH[g][t] = cvt_bf8(h0v, h1v);
      f32x4 i0v = *(const f32x4*)(pi + t * 32);
      f32x4 i1v = *(const f32x4*)(pi + t * 32 + 4);
      aI[g][t] = cvt_bf8(i0v, i1v);
    }
  }
  if (tid < 48) {
    const int g = tid >> 4, j = tid & 15;
    bI[g][j] = bih[l * G3 + g * HID + j0 + j];
    bH[g][j] = bhh[l * G3 + g * HID + j0 + j];
  }
  // h0 -> h_loc (f32) + blocked hbuf parity 0 (bf16, through-L3 store)
  {
    const int b = tid >> 2, jj = (tid & 3) << 2;
    f32x4 v = *(const f32x4*)(h0 + ((size_t)l * BATCH + b) * HID + j0 + jj);
    h_loc[b][jj] = v[0]; h_loc[b][jj + 1] = v[1];
    h_loc[b][jj + 2] = v[2]; h_loc[b][jj + 3] = v[3];
    bf16x4 p4; p4[0] = (bf16)v[0]; p4[1] = (bf16)v[1];
    p4[2] = (bf16)v[2]; p4[3] = (bf16)v[3];
    bf16* dst = hbuf + (size_t)(l * 2) * HBLK + wg * 1024 + b * 16 + jj;
    asm volatile("global_store_dwordx2 %0, %1, off sc0 sc1"
                 :: "v"(dst), "v"(p4) : "memory");
  }
  asm volatile("s_waitcnt vmcnt(0)" ::: "memory");  // h0 stores at L3
  __syncthreads();
  if (tid == 0)
    __hip_atomic_store(&flg[(l * 64 + wg) * 32], 1,
                       __ATOMIC_RELAXED, __HIP_MEMORY_SCOPE_AGENT);

  // per-lane byte offset within an h snapshot block (blocked layout)
  const int base_lane = (wave * 16 + (quad >> 1)) * 1024 + l16 * 16 + (quad & 1) * 8;
  const unsigned base_byte = (unsigned)base_lane * 2;

  for (int s = 0; s < SEQ; s++) {
    // ---- phase-1: wave0 waits peers done s-1; wave1 waits downstream drain ----
    if (wave == 0) {
      const int* fp = flg + (l * 64 + lane) * 32;
      const int tgt = s + 1;
      while (!__all(__hip_atomic_load(fp, __ATOMIC_RELAXED,
                                      __HIP_MEMORY_SCOPE_AGENT) >= tgt))
        __builtin_amdgcn_s_sleep(1);
    } else if (wave == 1 && l + 1 < LAYERS) {
      const int* fp = flg + ((l + 1) * 64 + lane) * 32;
      while (!__all(__hip_atomic_load(fp, __ATOMIC_RELAXED,
                                      __HIP_MEMORY_SCOPE_AGENT) >= s))
        __builtin_amdgcn_s_sleep(1);
    }
    __syncthreads();

    f32x4 aR[4], aZ[4], aGN[4], aIN[4];
#pragma unroll
    for (int nt = 0; nt < 4; nt++) {
      aR[nt] = (f32x4)(0.0f); aZ[nt] = (f32x4)(0.0f);
      aGN[nt] = (f32x4)(0.0f); aIN[nt] = (f32x4)(0.0f);
    }

    // ---- h-side: batch-issue 32 coherent loads, counted waits, MFMA ----
    {
      const bf16* hbase = hbuf + (size_t)(l * 2 + (s & 1)) * HBLK;
      bf16x8 hv[8][4];
#pragma unroll
      for (int t = 0; t < 8; t++) {
        const unsigned voff = base_byte + t * 4096;
        GLOAD4(hv[t][0], voff, hbase, 0);
        GLOAD4(hv[t][1], voff, hbase, 512);
        GLOAD4(hv[t][2], voff, hbase, 1024);
        GLOAD4(hv[t][3], voff, hbase, 1536);
      }
      SWAITV(16);  // first 16 loads (t=0..3) landed
#pragma unroll
      for (int t = 0; t < 4; t++)
#pragma unroll
        for (int nt = 0; nt < 4; nt++) {
          aR[nt]  = __builtin_amdgcn_mfma_f32_16x16x32_bf16(aH[0][t], hv[t][nt], aR[nt], 0, 0, 0);
          aZ[nt]  = __builtin_amdgcn_mfma_f32_16x16x32_bf16(aH[1][t], hv[t][nt], aZ[nt], 0, 0, 0);
          aGN[nt] = __builtin_amdgcn_mfma_f32_16x16x32_bf16(aH[2][t], hv[t][nt], aGN[nt], 0, 0, 0);
        }
      SWAITV(0);
#pragma unroll
      for (int t = 4; t < 8; t++)
#pragma unroll
        for (int nt = 0; nt < 4; nt++) {
          aR[nt]  = __builtin_amdgcn_mfma_f32_16x16x32_bf16(aH[0][t], hv[t][nt], aR[nt], 0, 0, 0);
          aZ[nt]  = __builtin_amdgcn_mfma_f32_16x16x32_bf16(aH[1][t], hv[t][nt], aZ[nt], 0, 0, 0);
          aGN[nt] = __builtin_amdgcn_mfma_f32_16x16x32_bf16(aH[2][t], hv[t][nt], aGN[nt], 0, 0, 0);
        }
    }

    // ---- x-side ----
    if (l > 0) {
      // phase-2 wait: upstream completed step s
      if (wave == 0) {
        const int* fp = flg + ((l - 1) * 64 + lane) * 32;
        const int tgt = s + 2;
        while (!__all(__hip_atomic_load(fp, __ATOMIC_RELAXED,
                                        __HIP_MEMORY_SCOPE_AGENT) >= tgt))
          __builtin_amdgcn_s_sleep(1);
      }
      __syncthreads();
      const bf16* ibase = hbuf + (size_t)((l - 1) * 2 + ((s + 1) & 1)) * HBLK;
      bf16x8 xv[8][4];
#pragma unroll
      for (int t = 0; t < 8; t++) {
        const unsigned voff = base_byte + t * 4096;
        GLOAD4(xv[t][0], voff, ibase, 0);
        GLOAD4(xv[t][1], voff, ibase, 512);
        GLOAD4(xv[t][2], voff, ibase, 1024);
        GLOAD4(xv[t][3], voff, ibase, 1536);
      }
      SWAITV(16);
#pragma unroll
      for (int t = 0; t < 4; t++)
#pragma unroll
        for (int nt = 0; nt < 4; nt++) {
          aR[nt]  = __builtin_amdgcn_mfma_f32_16x16x32_bf16(aI[0][t], xv[t][nt], aR[nt], 0, 0, 0);
          aZ[nt]  = __builtin_amdgcn_mfma_f32_16x16x32_bf16(aI[1][t], xv[t][nt], aZ[nt], 0, 0, 0);
          aIN[nt] = __builtin_amdgcn_mfma_f32_16x16x32_bf16(aI[2][t], xv[t][nt], aIN[nt], 0, 0, 0);
        }
      SWAITV(0);
#pragma unroll
      for (int t = 4; t < 8; t++)
#pragma unroll
        for (int nt = 0; nt < 4; nt++) {
          aR[nt]  = __builtin_amdgcn_mfma_f32_16x16x32_bf16(aI[0][t], xv[t][nt], aR[nt], 0, 0, 0);
          aZ[nt]  = __builtin_amdgcn_mfma_f32_16x16x32_bf16(aI[1][t], xv[t][nt], aZ[nt], 0, 0, 0);
          aIN[nt] = __builtin_amdgcn_mfma_f32_16x16x32_bf16(aI[2][t], xv[t][nt], aIN[nt], 0, 0, 0);
        }
    } else {
      // layer 0: xb is read-only & L2-resident now (no fences) -> cached loads
      const bf16* xBlk = xb + (size_t)s * HBLK + base_lane;
#pragma unroll
      for (int t = 0; t < 8; t++) {
        bf16x8 bx[4];
#pragma unroll
        for (int nt = 0; nt < 4; nt++)
          bx[nt] = *(const bf16x8*)(xBlk + t * 2048 + nt * 256);
#pragma unroll
        for (int nt = 0; nt < 4; nt++) {
          aR[nt]  = __builtin_amdgcn_mfma_f32_16x16x32_bf16(aI[0][t], bx[nt], aR[nt], 0, 0, 0);
          aZ[nt]  = __builtin_amdgcn_mfma_f32_16x16x32_bf16(aI[1][t], bx[nt], aZ[nt], 0, 0, 0);
          aIN[nt] = __builtin_amdgcn_mfma_f32_16x16x32_bf16(aI[2][t], bx[nt], aIN[nt], 0, 0, 0);
        }
      }
    }

    // ---- phase A: r,z,gh_n partials; reduce across waves ----
#pragma unroll
    for (int nt = 0; nt < 4; nt++)
#pragma unroll
      for (int r = 0; r < 4; r++) {
        part[wave][0][nt][quad * 4 + r][l16] = aR[nt][r];
        part[wave][1][nt][quad * 4 + r][l16] = aZ[nt][r];
        part[wave][2][nt][quad * 4 + r][l16] = aGN[nt][r];
      }
    __syncthreads();
    float rp[4], zp[4], gnp[4];
#pragma unroll
    for (int u = 0; u < 4; u++) {
      const int e = tid + u * 256;
      const int j = e & 15, b = e >> 4;
      const int nt = b >> 4, bl = b & 15;
      float sr = 0.f, sz = 0.f, sn = 0.f;
#pragma unroll
      for (int w = 0; w < 4; w++) {
        sr += part[w][0][nt][j][bl];
        sz += part[w][1][nt][j][bl];
        sn += part[w][2][nt][j][bl];
      }
      rp[u] = sr; zp[u] = sz; gnp[u] = sn;
    }
    __syncthreads();

    // ---- phase B: gi_n partials (reuse plane 0) + nonlinearity ----
#pragma unroll
    for (int nt = 0; nt < 4; nt++)
#pragma unroll
      for (int r = 0; r < 4; r++)
        part[wave][0][nt][quad * 4 + r][l16] = aIN[nt][r];
    __syncthreads();
#pragma unroll
    for (int u = 0; u < 4; u++) {
      const int e = tid + u * 256;
      const int j = e & 15, b = e >> 4;
      const int nt = b >> 4, bl = b & 15;
      float gin = 0.f;
#pragma unroll
      for (int w = 0; w < 4; w++) gin += part[w][0][nt][j][bl];
      const float r = 1.f / (1.f + __expf(-(rp[u] + bI[0][j] + bH[0][j])));
      const float z = 1.f / (1.f + __expf(-(zp[u] + bI[1][j] + bH[1][j])));
      const float n = tanhf(gin + bI[2][j] + r * (gnp[u] + bH[2][j]));
      const float hp = h_loc[b][j];
      h_loc[b][j] = (1.f - z) * n + z * hp;
    }
    __syncthreads();

    // ---- store pass: 8B/thread coalesced through-L3 h store (+ out for l==2) ----
    {
      const int b = tid >> 2, jj = (tid & 3) << 2;
      const float v0 = h_loc[b][jj],     v1 = h_loc[b][jj + 1];
      const float v2 = h_loc[b][jj + 2], v3 = h_loc[b][jj + 3];
      bf16x4 p4; p4[0] = (bf16)v0; p4[1] = (bf16)v1;
      p4[2] = (bf16)v2; p4[3] = (bf16)v3;
      bf16* dst = hbuf + (size_t)(l * 2 + ((s + 1) & 1)) * HBLK
                  + wg * 1024 + b * 16 + jj;
      asm volatile("global_store_dwordx2 %0, %1, off sc0 sc1"
                   :: "v"(dst), "v"(p4) : "memory");
      if (l == 2) {
        f32x4 ov; ov[0] = v0; ov[1] = v1; ov[2] = v2; ov[3] = v3;
        *(f32x4*)(out + ((size_t)s * BATCH + b) * HID + j0 + jj) = ov;
      }
    }
    asm volatile("s_waitcnt vmcnt(0)" ::: "memory");  // h at L3 before flag
    __syncthreads();
    if (tid == 0)
      __hip_atomic_store(&flg[(l * 64 + wg) * 32], s + 2,
                         __ATOMIC_RELAXED, __HIP_MEMORY_SCOPE_AGENT);
  }
}

extern "C" void kernel_launch(void* const* d_in, const int* in_sizes, int n_in,
                              void* d_out, int out_size, void* d_ws, size_t ws_size,
                              hipStream_t stream) {
  const float* x   = (const float*)d_in[0];
  const float* h0  = (const float*)d_in[1];
  const float* wih = (const float*)d_in[2];
  const float* whh = (const float*)d_in[3];
  const float* bih = (const float*)d_in[4];
  const float* bhh = (const float*)d_in[5];
  float* out = (float*)d_out;

  char* ws = (char*)d_ws;
  size_t off = 0;
  bf16* xb   = (bf16*)(ws + off); off += (size_t)SEQ * BATCH * HID * sizeof(bf16);   // 67 MB
  bf16* hbuf = (bf16*)(ws + off); off += (size_t)LAYERS * 2 * HBLK * sizeof(bf16);   // 768 KB
  int* flg   = (int*)(ws + off);  off += LAYERS * NWGL * 32 * sizeof(int);           // 24 KB

  hipMemsetAsync(flg, 0, LAYERS * NWGL * 32 * sizeof(int), stream);
  x_to_bf16_blk<<<(SEQ * 64 * 64) / 256, 256, 0, stream>>>(x, xb);
  gru_persist<<<LAYERS * NWGL, 256, 0, stream>>>(xb, h0, wih, whh, bih, bhh,
                                                 out, hbuf, flg);
}

// Round 2
// 3547.803 us; speedup vs baseline: 3.7154x; 1.5639x over previous
//
#include <hip/hip_runtime.h>
#include <hip/hip_bf16.h>
#include <math.h>

#define SEQ 512
#define BATCH 64
#define HID 1024
#define G3 3072
#define LAYERS 3
#define JW 16      // hidden dims owned per WG
#define NWGL 64    // WGs per layer group
#define HBLK 65536 // elements per h snapshot: 64 kblocks x 64 batch x 16

typedef __bf16 bf16;
typedef __bf16 bf16x8 __attribute__((ext_vector_type(8)));
typedef __bf16 bf16x4 __attribute__((ext_vector_type(4)));
typedef float f32x4 __attribute__((ext_vector_type(4)));

static __device__ inline bf16x8 cvt_bf8(f32x4 a, f32x4 b) {
  bf16x8 r;
  r[0] = (bf16)a[0]; r[1] = (bf16)a[1]; r[2] = (bf16)a[2]; r[3] = (bf16)a[3];
  r[4] = (bf16)b[0]; r[5] = (bf16)b[1]; r[6] = (bf16)b[2]; r[7] = (bf16)b[3];
  return r;
}

// x[s][b][k] (f32) -> xb[s][k>>4][b][k&15] (bf16): blocked layout matching hbuf.
__global__ __launch_bounds__(256) void x_to_bf16_blk(const float* __restrict__ x,
                                                     bf16* __restrict__ xb) {
  const int g = blockIdx.x * 256 + threadIdx.x;
  const int b = g & 63;
  const int kb = (g >> 6) & 63;
  const int s = g >> 12;
  const float* src = x + ((size_t)s * 64 + b) * 1024 + kb * 16;
  bf16* dst = xb + (size_t)s * HBLK + kb * 1024 + b * 16;
  f32x4 a0 = *(const f32x4*)(src);
  f32x4 a1 = *(const f32x4*)(src + 4);
  f32x4 a2 = *(const f32x4*)(src + 8);
  f32x4 a3 = *(const f32x4*)(src + 12);
  *(bf16x8*)(dst) = cvt_bf8(a0, a1);
  *(bf16x8*)(dst + 8) = cvt_bf8(a2, a3);
}

// coherent (bypass L1/L2) and plain 16B loads: SGPR base + 32b voffset + imm
#define GLOAD4C(dst, voff, sbase, IMM)                                        \
  asm volatile("global_load_dwordx4 %0, %1, %2 offset:" #IMM " sc0 sc1"       \
               : "=v"(dst) : "v"(voff), "s"(sbase) : "memory")
#define GLOAD4P(dst, voff, sbase, IMM)                                        \
  asm volatile("global_load_dwordx4 %0, %1, %2 offset:" #IMM                  \
               : "=v"(dst) : "v"(voff), "s"(sbase) : "memory")
#define VMWAIT(N)                                                             \
  do {                                                                        \
    asm volatile("s_waitcnt vmcnt(" #N ")" ::: "memory");                     \
    __builtin_amdgcn_sched_barrier(0);                                        \
  } while (0)

// R6: single-poll / single-load-exposure / single-LDS-pass step.
//  poll(3 waves concurrent) -> barrier -> issue 48 loads -> counted-vmcnt MFMA
//  -> 16x ds_write_b128 -> barrier -> 16x ds_read_b128 reduce + epilogue in
//  registers (h carry in VGPRs) -> coalesced store -> drain -> barrier -> flag
__global__ __launch_bounds__(256, 1) void gru_persist(
    const bf16*  __restrict__ xb,    // [SEQ][64 kb][64 b][16] bf16
    const float* __restrict__ h0,    // [LAYERS][BATCH][HID]
    const float* __restrict__ wih,   // [LAYERS*G3][HID]
    const float* __restrict__ whh,   // [LAYERS*G3][HID]
    const float* __restrict__ bih,   // [LAYERS*G3]
    const float* __restrict__ bhh,   // [LAYERS*G3]
    float* __restrict__ out,         // [SEQ][BATCH][HID]
    bf16*  __restrict__ hbuf,        // [LAYERS][2][64 kb][64 b][16] bf16
    int*   __restrict__ flg)         // [LAYERS][NWGL] flags, 32-int stride
{
  const int l    = blockIdx.x >> 6;
  const int wg   = blockIdx.x & 63;
  const int j0   = wg * JW;
  const int tid  = threadIdx.x;
  const int lane = tid & 63, wave = tid >> 6;
  const int quad = lane >> 4, l16 = lane & 15;
  const int kr   = wave * 256;   // this wave's K range

  // [wave][gate R,Z,GN,IN][nt][col=batch%16][row j + pad4] -> b128 LDS ops
  __shared__ __align__(16) float part[4][4][4][16][20];  // 80 KiB
  __shared__ __align__(16) float bI[3][JW], bH[3][JW];

  // ---- prologue: both weight slices -> register A-fragments ----
  const float* WhhL = whh + (size_t)l * G3 * HID;
  const float* WihL = wih + (size_t)l * G3 * HID;
  bf16x8 aH[3][8], aI[3][8];
#pragma unroll
  for (int g = 0; g < 3; g++) {
    const int row = g * HID + j0 + l16;
    const float* ph = WhhL + (size_t)row * HID + kr + quad * 8;
    const float* pi = WihL + (size_t)row * HID + kr + quad * 8;
#pragma unroll
    for (int t = 0; t < 8; t++) {
      f32x4 h0v = *(const f32x4*)(ph + t * 32);
      f32x4 h1v = *(const f32x4*)(ph + t * 32 + 4);
      aH[g][t] = cvt_bf8(h0v, h1v);
      f32x4 i0v = *(const f32x4*)(pi + t * 32);
      f32x4 i1v = *(const f32x4*)(pi + t * 32 + 4);
      aI[g][t] = cvt_bf8(i0v, i1v);
    }
  }
  if (tid < 48) {
    const int g = tid >> 4, j = tid & 15;
    bI[g][j] = bih[l * G3 + g * HID + j0 + j];
    bH[g][j] = bhh[l * G3 + g * HID + j0 + j];
  }

  // thread's epilogue ownership: batch bown, 4 consecutive j (jg*4..jg*4+3)
  const int bown = tid >> 2, jg = tid & 3;
  const int ntb = bown >> 4, bl = bown & 15;

  // h carry in registers (f32) + blocked hbuf parity 0 (bf16 through-L3)
  f32x4 hprev = *(const f32x4*)(h0 + ((size_t)l * BATCH + bown) * HID + j0 + jg * 4);
  {
    bf16x4 p4; p4[0] = (bf16)hprev[0]; p4[1] = (bf16)hprev[1];
    p4[2] = (bf16)hprev[2]; p4[3] = (bf16)hprev[3];
    bf16* dst = hbuf + (size_t)(l * 2) * HBLK + wg * 1024 + bown * 16 + jg * 4;
    asm volatile("global_store_dwordx2 %0, %1, off sc0 sc1"
                 :: "v"(dst), "v"(p4) : "memory");
  }
  asm volatile("s_waitcnt vmcnt(0)" ::: "memory");
  __syncthreads();
  if (tid == 0)
    __hip_atomic_store(&flg[(l * 64 + wg) * 32], 1,
                       __ATOMIC_RELAXED, __HIP_MEMORY_SCOPE_AGENT);

  // per-lane byte offset within an h snapshot block (blocked layout)
  const int base_lane = (wave * 16 + (quad >> 1)) * 1024 + l16 * 16 + (quad & 1) * 8;
  const unsigned base_byte = (unsigned)base_lane * 2;

  for (int s = 0; s < SEQ; s++) {
    // ---- unified poll: 3 waves watch 3 conditions concurrently ----
    if (wave == 0) {            // own-layer peers completed s-1
      const int* fp = flg + (l * 64 + lane) * 32;
      const int tgt = s + 1;
      while (!__all(__hip_atomic_load(fp, __ATOMIC_RELAXED,
                                      __HIP_MEMORY_SCOPE_AGENT) >= tgt))
        __builtin_amdgcn_s_sleep(1);
    } else if (wave == 1 && l > 0) {  // upstream completed s
      const int* fp = flg + ((l - 1) * 64 + lane) * 32;
      const int tgt = s + 2;
      while (!__all(__hip_atomic_load(fp, __ATOMIC_RELAXED,
                                      __HIP_MEMORY_SCOPE_AGENT) >= tgt))
        __builtin_amdgcn_s_sleep(1);
    } else if (wave == 2 && l + 1 < LAYERS) {  // downstream drained our slot
      const int* fp = flg + ((l + 1) * 64 + lane) * 32;
      const int tgt = s;
      while (!__all(__hip_atomic_load(fp, __ATOMIC_RELAXED,
                                      __HIP_MEMORY_SCOPE_AGENT) >= tgt))
        __builtin_amdgcn_s_sleep(1);
    }
    __syncthreads();

    f32x4 acc[4][4];  // [R,Z,GN,IN][nt]
#pragma unroll
    for (int g = 0; g < 4; g++)
#pragma unroll
      for (int nt = 0; nt < 4; nt++) acc[g][nt] = (f32x4)(0.0f);

    // ---- batch-issue: 32 h loads + first 16 x loads ----
    bf16x8 hv[8][4], xv[8][4];
    {
      const bf16* hbase = hbuf + (size_t)(l * 2 + (s & 1)) * HBLK;
#pragma unroll
      for (int t = 0; t < 8; t++) {
        const unsigned voff = base_byte + t * 4096;
        GLOAD4C(hv[t][0], voff, hbase, 0);
        GLOAD4C(hv[t][1], voff, hbase, 512);
        GLOAD4C(hv[t][2], voff, hbase, 1024);
        GLOAD4C(hv[t][3], voff, hbase, 1536);
      }
    }
    const bf16* ibase = (l > 0)
        ? (hbuf + (size_t)((l - 1) * 2 + ((s + 1) & 1)) * HBLK)
        : (xb + (size_t)s * HBLK);
    if (l > 0) {
#pragma unroll
      for (int t = 0; t < 4; t++) {
        const unsigned voff = base_byte + t * 4096;
        GLOAD4C(xv[t][0], voff, ibase, 0);
        GLOAD4C(xv[t][1], voff, ibase, 512);
        GLOAD4C(xv[t][2], voff, ibase, 1024);
        GLOAD4C(xv[t][3], voff, ibase, 1536);
      }
    } else {
#pragma unroll
      for (int t = 0; t < 4; t++) {
        const unsigned voff = base_byte + t * 4096;
        GLOAD4P(xv[t][0], voff, ibase, 0);
        GLOAD4P(xv[t][1], voff, ibase, 512);
        GLOAD4P(xv[t][2], voff, ibase, 1024);
        GLOAD4P(xv[t][3], voff, ibase, 1536);
      }
    }

    // ---- h-side MFMA (counted waits; 48 loads in flight) ----
    VMWAIT(32);  // hv t0..3 landed
#pragma unroll
    for (int t = 0; t < 4; t++)
#pragma unroll
      for (int nt = 0; nt < 4; nt++) {
        acc[0][nt] = __builtin_amdgcn_mfma_f32_16x16x32_bf16(aH[0][t], hv[t][nt], acc[0][nt], 0, 0, 0);
        acc[1][nt] = __builtin_amdgcn_mfma_f32_16x16x32_bf16(aH[1][t], hv[t][nt], acc[1][nt], 0, 0, 0);
        acc[2][nt] = __builtin_amdgcn_mfma_f32_16x16x32_bf16(aH[2][t], hv[t][nt], acc[2][nt], 0, 0, 0);
      }
    VMWAIT(16);  // hv t4..7 landed
#pragma unroll
    for (int t = 4; t < 8; t++)
#pragma unroll
      for (int nt = 0; nt < 4; nt++) {
        acc[0][nt] = __builtin_amdgcn_mfma_f32_16x16x32_bf16(aH[0][t], hv[t][nt], acc[0][nt], 0, 0, 0);
        acc[1][nt] = __builtin_amdgcn_mfma_f32_16x16x32_bf16(aH[1][t], hv[t][nt], acc[1][nt], 0, 0, 0);
        acc[2][nt] = __builtin_amdgcn_mfma_f32_16x16x32_bf16(aH[2][t], hv[t][nt], acc[2][nt], 0, 0, 0);
      }

    // ---- issue remaining 16 x loads (hv regs now dead) ----
    if (l > 0) {
#pragma unroll
      for (int t = 4; t < 8; t++) {
        const unsigned voff = base_byte + t * 4096;
        GLOAD4C(xv[t][0], voff, ibase, 0);
        GLOAD4C(xv[t][1], voff, ibase, 512);
        GLOAD4C(xv[t][2], voff, ibase, 1024);
        GLOAD4C(xv[t][3], voff, ibase, 1536);
      }
    } else {
#pragma unroll
      for (int t = 4; t < 8; t++) {
        const unsigned voff = base_byte + t * 4096;
        GLOAD4P(xv[t][0], voff, ibase, 0);
        GLOAD4P(xv[t][1], voff, ibase, 512);
        GLOAD4P(xv[t][2], voff, ibase, 1024);
        GLOAD4P(xv[t][3], voff, ibase, 1536);
      }
    }

    // ---- x-side MFMA ----
    VMWAIT(16);  // xv t0..3 landed
#pragma unroll
    for (int t = 0; t < 4; t++)
#pragma unroll
      for (int nt = 0; nt < 4; nt++) {
        acc[0][nt] = __builtin_amdgcn_mfma_f32_16x16x32_bf16(aI[0][t], xv[t][nt], acc[0][nt], 0, 0, 0);
        acc[1][nt] = __builtin_amdgcn_mfma_f32_16x16x32_bf16(aI[1][t], xv[t][nt], acc[1][nt], 0, 0, 0);
        acc[3][nt] = __builtin_amdgcn_mfma_f32_16x16x32_bf16(aI[2][t], xv[t][nt], acc[3][nt], 0, 0, 0);
      }
    VMWAIT(0);   // xv t4..7 landed
#pragma unroll
    for (int t = 4; t < 8; t++)
#pragma unroll
      for (int nt = 0; nt < 4; nt++) {
        acc[0][nt] = __builtin_amdgcn_mfma_f32_16x16x32_bf16(aI[0][t], xv[t][nt], acc[0][nt], 0, 0, 0);
        acc[1][nt] = __builtin_amdgcn_mfma_f32_16x16x32_bf16(aI[1][t], xv[t][nt], acc[1][nt], 0, 0, 0);
        acc[3][nt] = __builtin_amdgcn_mfma_f32_16x16x32_bf16(aI[2][t], xv[t][nt], acc[3][nt], 0, 0, 0);
      }

    // ---- single LDS pass: vectorized partials, all 4 gates ----
#pragma unroll
    for (int g = 0; g < 4; g++)
#pragma unroll
      for (int nt = 0; nt < 4; nt++)
        *(f32x4*)&part[wave][g][nt][l16][quad * 4] = acc[g][nt];
    __syncthreads();

    // ---- reduce across waves + epilogue, all in registers ----
    f32x4 sG[4];
#pragma unroll
    for (int g = 0; g < 4; g++) {
      f32x4 sum = *(const f32x4*)&part[0][g][ntb][bl][jg * 4];
#pragma unroll
      for (int w = 1; w < 4; w++)
        sum += *(const f32x4*)&part[w][g][ntb][bl][jg * 4];
      sG[g] = sum;
    }
    const f32x4 bI0 = *(const f32x4*)&bI[0][jg * 4];
    const f32x4 bI1 = *(const f32x4*)&bI[1][jg * 4];
    const f32x4 bI2 = *(const f32x4*)&bI[2][jg * 4];
    const f32x4 bH0 = *(const f32x4*)&bH[0][jg * 4];
    const f32x4 bH1 = *(const f32x4*)&bH[1][jg * 4];
    const f32x4 bH2 = *(const f32x4*)&bH[2][jg * 4];
    f32x4 hn;
#pragma unroll
    for (int c = 0; c < 4; c++) {
      const float r = 1.f / (1.f + __expf(-(sG[0][c] + bI0[c] + bH0[c])));
      const float z = 1.f / (1.f + __expf(-(sG[1][c] + bI1[c] + bH1[c])));
      const float n = tanhf(sG[3][c] + bI2[c] + r * (sG[2][c] + bH2[c]));
      hn[c] = (1.f - z) * n + z * hprev[c];
    }
    hprev = hn;

    // ---- coalesced stores: 8B bf16 h (+16B f32 out on last layer) ----
    {
      bf16x4 p4; p4[0] = (bf16)hn[0]; p4[1] = (bf16)hn[1];
      p4[2] = (bf16)hn[2]; p4[3] = (bf16)hn[3];
      bf16* dst = hbuf + (size_t)(l * 2 + ((s + 1) & 1)) * HBLK
                  + wg * 1024 + bown * 16 + jg * 4;
      asm volatile("global_store_dwordx2 %0, %1, off sc0 sc1"
                   :: "v"(dst), "v"(p4) : "memory");
      if (l == 2)
        *(f32x4*)(out + ((size_t)s * BATCH + bown) * HID + j0 + jg * 4) = hn;
    }
    asm volatile("s_waitcnt vmcnt(0)" ::: "memory");  // h at L3 before flag
    __syncthreads();
    if (tid == 0)
      __hip_atomic_store(&flg[(l * 64 + wg) * 32], s + 2,
                         __ATOMIC_RELAXED, __HIP_MEMORY_SCOPE_AGENT);
  }
}

extern "C" void kernel_launch(void* const* d_in, const int* in_sizes, int n_in,
                              void* d_out, int out_size, void* d_ws, size_t ws_size,
                              hipStream_t stream) {
  const float* x   = (const float*)d_in[0];
  const float* h0  = (const float*)d_in[1];
  const float* wih = (const float*)d_in[2];
  const float* whh = (const float*)d_in[3];
  const float* bih = (const float*)d_in[4];
  const float* bhh = (const float*)d_in[5];
  float* out = (float*)d_out;

  char* ws = (char*)d_ws;
  size_t off = 0;
  bf16* xb   = (bf16*)(ws + off); off += (size_t)SEQ * BATCH * HID * sizeof(bf16);   // 67 MB
  bf16* hbuf = (bf16*)(ws + off); off += (size_t)LAYERS * 2 * HBLK * sizeof(bf16);   // 768 KB
  int* flg   = (int*)(ws + off);  off += LAYERS * NWGL * 32 * sizeof(int);           // 24 KB

  hipMemsetAsync(flg, 0, LAYERS * NWGL * 32 * sizeof(int), stream);
  x_to_bf16_blk<<<(SEQ * 64 * 64) / 256, 256, 0, stream>>>(x, xb);
  gru_persist<<<LAYERS * NWGL, 256, 0, stream>>>(xb, h0, wih, whh, bih, bhh,
                                                 out, hbuf, flg);
}

// Round 4
// 3139.312 us; speedup vs baseline: 4.1989x; 1.1301x over previous
//
#include <hip/hip_runtime.h>
#include <hip/hip_bf16.h>
#include <math.h>

#define SEQ 512
#define BATCH 64
#define HID 1024
#define G3 3072
#define LAYERS 3
#define JW 16      // hidden dims owned per WG
#define NWGL 64    // WGs per layer group
#define HBLK 65536 // elements per h snapshot: 64 kblocks x 64 batch x 16

typedef __bf16 bf16;
typedef __bf16 bf16x8 __attribute__((ext_vector_type(8)));
typedef __bf16 bf16x4 __attribute__((ext_vector_type(4)));
typedef float f32x4 __attribute__((ext_vector_type(4)));

static __device__ inline bf16x8 cvt_bf8(f32x4 a, f32x4 b) {
  bf16x8 r;
  r[0] = (bf16)a[0]; r[1] = (bf16)a[1]; r[2] = (bf16)a[2]; r[3] = (bf16)a[3];
  r[4] = (bf16)b[0]; r[5] = (bf16)b[1]; r[6] = (bf16)b[2]; r[7] = (bf16)b[3];
  return r;
}

// x[s][b][k] (f32) -> xb[s][k>>4][b][k&15] (bf16): blocked layout matching hbuf.
__global__ __launch_bounds__(256) void x_to_bf16_blk(const float* __restrict__ x,
                                                     bf16* __restrict__ xb) {
  const int g = blockIdx.x * 256 + threadIdx.x;
  const int b = g & 63;
  const int kb = (g >> 6) & 63;
  const int s = g >> 12;
  const float* src = x + ((size_t)s * 64 + b) * 1024 + kb * 16;
  bf16* dst = xb + (size_t)s * HBLK + kb * 1024 + b * 16;
  f32x4 a0 = *(const f32x4*)(src);
  f32x4 a1 = *(const f32x4*)(src + 4);
  f32x4 a2 = *(const f32x4*)(src + 8);
  f32x4 a3 = *(const f32x4*)(src + 12);
  *(bf16x8*)(dst) = cvt_bf8(a0, a1);
  *(bf16x8*)(dst + 8) = cvt_bf8(a2, a3);
}

// coherent (bypass L1/L2) and plain 16B loads: SGPR base + 32b voffset + imm
#define GLOAD4C(dst, voff, sbase, IMM)                                        \
  asm volatile("global_load_dwordx4 %0, %1, %2 offset:" #IMM " sc0 sc1"       \
               : "=v"(dst) : "v"(voff), "s"(sbase) : "memory")
#define GLOAD4P(dst, voff, sbase, IMM)                                        \
  asm volatile("global_load_dwordx4 %0, %1, %2 offset:" #IMM                  \
               : "=v"(dst) : "v"(voff), "s"(sbase) : "memory")
#define VMWAIT(N)                                                             \
  do {                                                                        \
    asm volatile("s_waitcnt vmcnt(" #N ")" ::: "memory");                     \
    __builtin_amdgcn_sched_barrier(0);                                        \
  } while (0)

// R8 (= R7 resubmit + finer waits + out-store off the drain path).
// x-first, per-wave subset polls, drain snapshot, register biases.
// Critical path/step: peer observe -> 32 h loads -> h-MFMA -> reduce ->
// epilogue -> store -> flag. x-side + drain hidden under the peer wait.
__global__ __launch_bounds__(256, 1) void gru_persist(
    const bf16*  __restrict__ xb,    // [SEQ][64 kb][64 b][16] bf16
    const float* __restrict__ h0,    // [LAYERS][BATCH][HID]
    const float* __restrict__ wih,   // [LAYERS*G3][HID]
    const float* __restrict__ whh,   // [LAYERS*G3][HID]
    const float* __restrict__ bih,   // [LAYERS*G3]
    const float* __restrict__ bhh,   // [LAYERS*G3]
    float* __restrict__ out,         // [SEQ][BATCH][HID]
    bf16*  __restrict__ hbuf,        // [LAYERS][2][64 kb][64 b][16] bf16
    int*   __restrict__ flg)         // [LAYERS][NWGL] flags, 32-int stride
{
  const int l    = blockIdx.x >> 6;
  const int wg   = blockIdx.x & 63;
  const int j0   = wg * JW;
  const int tid  = threadIdx.x;
  const int lane = tid & 63, wave = tid >> 6;
  const int quad = lane >> 4, l16 = lane & 15;
  const int kr   = wave * 256;   // this wave's K range

  // [wave][gate R,Z,GN,IN][nt][col=batch%16][row j + pad] -> b128 LDS ops
  __shared__ __align__(16) float part[4][4][4][16][20];  // 80 KiB

  // ---- prologue: both weight slices -> register A-fragments ----
  const float* WhhL = whh + (size_t)l * G3 * HID;
  const float* WihL = wih + (size_t)l * G3 * HID;
  bf16x8 aH[3][8], aI[3][8];
#pragma unroll
  for (int g = 0; g < 3; g++) {
    const int row = g * HID + j0 + l16;
    const float* ph = WhhL + (size_t)row * HID + kr + quad * 8;
    const float* pi = WihL + (size_t)row * HID + kr + quad * 8;
#pragma unroll
    for (int t = 0; t < 8; t++) {
      f32x4 h0v = *(const f32x4*)(ph + t * 32);
      f32x4 h1v = *(const f32x4*)(ph + t * 32 + 4);
      aH[g][t] = cvt_bf8(h0v, h1v);
      f32x4 i0v = *(const f32x4*)(pi + t * 32);
      f32x4 i1v = *(const f32x4*)(pi + t * 32 + 4);
      aI[g][t] = cvt_bf8(i0v, i1v);
    }
  }

  // thread's epilogue ownership: batch bown, 4 consecutive j (jg*4..jg*4+3)
  const int bown = tid >> 2, jg = tid & 3;
  const int ntb = bown >> 4, bl = bown & 15;

  // biases in registers (uniform per thread across steps)
  const f32x4 bI0 = *(const f32x4*)(bih + l * G3 + 0 * HID + j0 + jg * 4);
  const f32x4 bI1 = *(const f32x4*)(bih + l * G3 + 1 * HID + j0 + jg * 4);
  const f32x4 bI2 = *(const f32x4*)(bih + l * G3 + 2 * HID + j0 + jg * 4);
  const f32x4 bH0 = *(const f32x4*)(bhh + l * G3 + 0 * HID + j0 + jg * 4);
  const f32x4 bH1 = *(const f32x4*)(bhh + l * G3 + 1 * HID + j0 + jg * 4);
  const f32x4 bH2 = *(const f32x4*)(bhh + l * G3 + 2 * HID + j0 + jg * 4);

  // h carry in registers (f32) + blocked hbuf parity 0 (bf16 through-L3)
  f32x4 hprev = *(const f32x4*)(h0 + ((size_t)l * BATCH + bown) * HID + j0 + jg * 4);
  {
    bf16x4 p4; p4[0] = (bf16)hprev[0]; p4[1] = (bf16)hprev[1];
    p4[2] = (bf16)hprev[2]; p4[3] = (bf16)hprev[3];
    bf16* dst = hbuf + (size_t)(l * 2) * HBLK + wg * 1024 + bown * 16 + jg * 4;
    asm volatile("global_store_dwordx2 %0, %1, off sc0 sc1"
                 :: "v"(dst), "v"(p4) : "memory");
  }
  asm volatile("s_waitcnt vmcnt(0)" ::: "memory");
  __syncthreads();
  if (tid == 0)
    __hip_atomic_store(&flg[(l * 64 + wg) * 32], 1,
                       __ATOMIC_RELAXED, __HIP_MEMORY_SCOPE_AGENT);

  // poll pointers: each wave watches exactly its 16 producers
  const int sub = (wave << 4) + l16;                       // producer WG id
  const int* fpPeer = flg + (l * 64 + sub) * 32;
  const int* fpUp   = (l > 0) ? flg + ((l - 1) * 64 + sub) * 32 : nullptr;
  const int* dpDown = (l + 1 < LAYERS) ? flg + ((l + 1) * 64 + lane) * 32 : nullptr;

  // per-lane byte offset within an h snapshot block (blocked layout)
  const int base_lane = (wave * 16 + (quad >> 1)) * 1024 + l16 * 16 + (quad & 1) * 8;
  const unsigned base_byte = (unsigned)base_lane * 2;

  for (int s = 0; s < SEQ; s++) {
    // ---- drain snapshot (resolved later, off critical path) ----
    int dsn = 0x7fffffff;
    if (l + 1 < LAYERS)
      asm volatile("global_load_dword %0, %1, off sc0 sc1"
                   : "=v"(dsn) : "v"(dpDown) : "memory");

    // ---- x producer wait (per-wave subset; upstream leads -> usually free) ----
    if (l > 0) {
      const int tgt = s + 2;
      while (!__all(__hip_atomic_load(fpUp, __ATOMIC_RELAXED,
                                      __HIP_MEMORY_SCOPE_AGENT) >= tgt))
        __builtin_amdgcn_s_sleep(1);
    }

    f32x4 acc[4][4];  // [R,Z,GN,IN][nt]
#pragma unroll
    for (int g = 0; g < 4; g++)
#pragma unroll
      for (int nt = 0; nt < 4; nt++) acc[g][nt] = (f32x4)(0.0f);

    bf16x8 bv[8][4];  // shared load block: x phase then h phase

    // ---- x loads + x-MFMA (R, Z, IN) ----
    const bf16* ibase = (l > 0)
        ? (hbuf + (size_t)((l - 1) * 2 + ((s + 1) & 1)) * HBLK)
        : (xb + (size_t)s * HBLK);
    if (l > 0) {
#pragma unroll
      for (int t = 0; t < 8; t++) {
        const unsigned voff = base_byte + t * 4096;
        GLOAD4C(bv[t][0], voff, ibase, 0);
        GLOAD4C(bv[t][1], voff, ibase, 512);
        GLOAD4C(bv[t][2], voff, ibase, 1024);
        GLOAD4C(bv[t][3], voff, ibase, 1536);
      }
    } else {
#pragma unroll
      for (int t = 0; t < 8; t++) {
        const unsigned voff = base_byte + t * 4096;
        GLOAD4P(bv[t][0], voff, ibase, 0);
        GLOAD4P(bv[t][1], voff, ibase, 512);
        GLOAD4P(bv[t][2], voff, ibase, 1024);
        GLOAD4P(bv[t][3], voff, ibase, 1536);
      }
    }
#define XMFMA2(T0, T1)                                                        \
  for (int t = T0; t <= T1; t++)                                              \
    for (int nt = 0; nt < 4; nt++) {                                          \
      acc[0][nt] = __builtin_amdgcn_mfma_f32_16x16x32_bf16(aI[0][t], bv[t][nt], acc[0][nt], 0, 0, 0); \
      acc[1][nt] = __builtin_amdgcn_mfma_f32_16x16x32_bf16(aI[1][t], bv[t][nt], acc[1][nt], 0, 0, 0); \
      acc[3][nt] = __builtin_amdgcn_mfma_f32_16x16x32_bf16(aI[2][t], bv[t][nt], acc[3][nt], 0, 0, 0); \
    }
    VMWAIT(24); XMFMA2(0, 1)
    VMWAIT(16); XMFMA2(2, 3)
    VMWAIT(8);  XMFMA2(4, 5)
    VMWAIT(0);  XMFMA2(6, 7)
#undef XMFMA2
    // IN gate (x-only) is final: park its partials now, off the tail
#pragma unroll
    for (int nt = 0; nt < 4; nt++)
      *(f32x4*)&part[wave][3][nt][l16][quad * 4] = acc[3][nt];

    // ---- peer wait (per-wave subset) -> h loads -> h-MFMA (R, Z, GN) ----
    {
      const int tgt = s + 1;
      while (!__all(__hip_atomic_load(fpPeer, __ATOMIC_RELAXED,
                                      __HIP_MEMORY_SCOPE_AGENT) >= tgt))
        __builtin_amdgcn_s_sleep(1);
    }
    const bf16* hbase = hbuf + (size_t)(l * 2 + (s & 1)) * HBLK;
#pragma unroll
    for (int t = 0; t < 8; t++) {
      const unsigned voff = base_byte + t * 4096;
      GLOAD4C(bv[t][0], voff, hbase, 0);
      GLOAD4C(bv[t][1], voff, hbase, 512);
      GLOAD4C(bv[t][2], voff, hbase, 1024);
      GLOAD4C(bv[t][3], voff, hbase, 1536);
    }
#define HMFMA2(T0, T1)                                                        \
  for (int t = T0; t <= T1; t++)                                              \
    for (int nt = 0; nt < 4; nt++) {                                          \
      acc[0][nt] = __builtin_amdgcn_mfma_f32_16x16x32_bf16(aH[0][t], bv[t][nt], acc[0][nt], 0, 0, 0); \
      acc[1][nt] = __builtin_amdgcn_mfma_f32_16x16x32_bf16(aH[1][t], bv[t][nt], acc[1][nt], 0, 0, 0); \
      acc[2][nt] = __builtin_amdgcn_mfma_f32_16x16x32_bf16(aH[2][t], bv[t][nt], acc[2][nt], 0, 0, 0); \
    }
    VMWAIT(24); HMFMA2(0, 1)
    VMWAIT(16); HMFMA2(2, 3)
    VMWAIT(8);  HMFMA2(4, 5)
    VMWAIT(0);  HMFMA2(6, 7)
#undef HMFMA2

    // ---- LDS partials for R,Z,GN; reduce; epilogue ----
#pragma unroll
    for (int g = 0; g < 3; g++)
#pragma unroll
      for (int nt = 0; nt < 4; nt++)
        *(f32x4*)&part[wave][g][nt][l16][quad * 4] = acc[g][nt];
    __syncthreads();

    f32x4 sG[4];
#pragma unroll
    for (int g = 0; g < 4; g++) {
      f32x4 sum = *(const f32x4*)&part[0][g][ntb][bl][jg * 4];
#pragma unroll
      for (int w = 1; w < 4; w++)
        sum += *(const f32x4*)&part[w][g][ntb][bl][jg * 4];
      sG[g] = sum;
    }
    f32x4 hn;
#pragma unroll
    for (int c = 0; c < 4; c++) {
      const float r = __fdividef(1.f, 1.f + __expf(-(sG[0][c] + bI0[c] + bH0[c])));
      const float z = __fdividef(1.f, 1.f + __expf(-(sG[1][c] + bI1[c] + bH1[c])));
      const float a = sG[3][c] + bI2[c] + r * (sG[2][c] + bH2[c]);
      const float e2 = __expf(2.f * a);
      const float n = 1.f - __fdividef(2.f, e2 + 1.f);
      hn[c] = (1.f - z) * n + z * hprev[c];
    }
    hprev = hn;

    // ---- drain verify (snapshot usually satisfied; condition is monotone) ----
    if (l + 1 < LAYERS && !__all(dsn >= s)) {
      while (!__all(__hip_atomic_load(dpDown, __ATOMIC_RELAXED,
                                      __HIP_MEMORY_SCOPE_AGENT) >= s))
        __builtin_amdgcn_s_sleep(1);
    }

    // ---- coalesced 8B bf16 h store; drain; flag; then out (off the path) ----
    {
      bf16x4 p4; p4[0] = (bf16)hn[0]; p4[1] = (bf16)hn[1];
      p4[2] = (bf16)hn[2]; p4[3] = (bf16)hn[3];
      bf16* dst = hbuf + (size_t)(l * 2 + ((s + 1) & 1)) * HBLK
                  + wg * 1024 + bown * 16 + jg * 4;
      asm volatile("global_store_dwordx2 %0, %1, off sc0 sc1"
                   :: "v"(dst), "v"(p4) : "memory");
    }
    asm volatile("s_waitcnt vmcnt(0)" ::: "memory");  // h at L3 before flag
    __syncthreads();
    if (tid == 0)
      __hip_atomic_store(&flg[(l * 64 + wg) * 32], s + 2,
                         __ATOMIC_RELAXED, __HIP_MEMORY_SCOPE_AGENT);
    if (l == 2)  // independent of inter-WG protocol; completes by kernel end
      *(f32x4*)(out + ((size_t)s * BATCH + bown) * HID + j0 + jg * 4) = hn;
  }
}

extern "C" void kernel_launch(void* const* d_in, const int* in_sizes, int n_in,
                              void* d_out, int out_size, void* d_ws, size_t ws_size,
                              hipStream_t stream) {
  const float* x   = (const float*)d_in[0];
  const float* h0  = (const float*)d_in[1];
  const float* wih = (const float*)d_in[2];
  const float* whh = (const float*)d_in[3];
  const float* bih = (const float*)d_in[4];
  const float* bhh = (const float*)d_in[5];
  float* out = (float*)d_out;

  char* ws = (char*)d_ws;
  size_t off = 0;
  bf16* xb   = (bf16*)(ws + off); off += (size_t)SEQ * BATCH * HID * sizeof(bf16);   // 67 MB
  bf16* hbuf = (bf16*)(ws + off); off += (size_t)LAYERS * 2 * HBLK * sizeof(bf16);   // 768 KB
  int* flg   = (int*)(ws + off);  off += LAYERS * NWGL * 32 * sizeof(int);           // 24 KB

  hipMemsetAsync(flg, 0, LAYERS * NWGL * 32 * sizeof(int), stream);
  x_to_bf16_blk<<<(SEQ * 64 * 64) / 256, 256, 0, stream>>>(x, xb);
  gru_persist<<<LAYERS * NWGL, 256, 0, stream>>>(xb, h0, wih, whh, bih, bhh,
                                                 out, hbuf, flg);
}